// Round 14
// baseline (189.918 us; speedup 1.0000x reference)
//
#include <hip/hip_runtime.h>

#define HID      1024
#define INTER    2048
#define STATE    128
#define NH       32
#define PDIM     64
#define KCONV    4
#define QCH      256
#define CONV_DIM (INTER + 2*STATE)      // 2304
#define DPROJ    (2*INTER + 2*STATE + NH) // 4384
#define DPROJ_PAD 4480                  // next multiple of 128
#define BATCH    2
#define SEQ      2048
#define NCHUNK   (SEQ / QCH)            // 8
#define BL       (BATCH * SEQ)          // 4096

typedef unsigned short u16;
typedef unsigned int   u32;
typedef u16 u16x8 __attribute__((ext_vector_type(8)));
typedef u16 u16x4 __attribute__((ext_vector_type(4)));
typedef float f32x4 __attribute__((ext_vector_type(4)));
typedef __bf16 bf16x8 __attribute__((ext_vector_type(8)));

static __device__ __forceinline__ u16 f2bf(float f) {
    u32 u = __float_as_uint(f);
    return (u16)((u + 0x7FFFu + ((u >> 16) & 1u)) >> 16);
}
static __device__ __forceinline__ float bf2f(u16 v) {
    return __uint_as_float(((u32)v) << 16);
}
static __device__ __forceinline__ void gload_lds16(const void* g, void* l) {
    __builtin_amdgcn_global_load_lds(
        (const __attribute__((address_space(1))) void*)g,
        (__attribute__((address_space(3))) void*)l, 16, 0, 0);
}
// swizzled LDS u16-index helpers (row-major tiles; byte XOR at 16B granularity)
static __device__ __forceinline__ int swz64(int row, int slot) {   // 64B rows
    return ((row * 64 + slot * 16) ^ (((row >> 1) & 3) << 4)) >> 1;
}
static __device__ __forceinline__ int swz128(int row, int slot) {  // 128B rows
    return ((row * 128 + slot * 16) ^ ((row & 7) << 4)) >> 1;
}

// ---------------------------------------------------------------------------
// Fused f32 -> bf16 conversion of hidden + in_proj_w (padded) + out_proj_w.
// ---------------------------------------------------------------------------
__global__ __launch_bounds__(256)
void cvt_all(const float* __restrict__ hidden, const float* __restrict__ w1,
             const float* __restrict__ w2, u16* __restrict__ Abf,
             u16* __restrict__ Wbf, u16* __restrict__ W2bf) {
    const long nA  = (long)BL * HID;
    const long nW  = (long)DPROJ_PAD * HID;
    const long nWr = (long)DPROJ * HID;
    const long nW2 = (long)HID * INTER;
    long i = ((long)blockIdx.x * 256 + threadIdx.x) * 8;
    const float* src; u16* dst; long j;
    if (i < nA)            { src = hidden; dst = Abf;  j = i; }
    else if (i < nA + nW)  { j = i - nA;
        if (j >= nWr) { *(u16x8*)&Wbf[j] = (u16x8)0; return; }
        src = w1; dst = Wbf; }
    else                   { j = i - nA - nW;
        if (j >= nW2) return;
        src = w2; dst = W2bf; }
    float4 a = *(const float4*)&src[j];
    float4 b = *(const float4*)&src[j + 4];
    u16x8 o;
    o[0] = f2bf(a.x); o[1] = f2bf(a.y); o[2] = f2bf(a.z); o[3] = f2bf(a.w);
    o[4] = f2bf(b.x); o[5] = f2bf(b.y); o[6] = f2bf(b.z); o[7] = f2bf(b.w);
    *(u16x8*)&dst[j] = o;
}

// ---------------------------------------------------------------------------
// in_proj GEMM — BM=256 x BN=128, 8 waves, BK=64, 2-phase (R12, passing).
// ---------------------------------------------------------------------------
__global__ __launch_bounds__(512)
void gemm_in_kernel(const u16* __restrict__ A, const u16* __restrict__ W,
                    u16* __restrict__ Cb, float* __restrict__ dtside,
                    int Nstride, int Nreal, int K) {
    __shared__ __attribute__((aligned(16))) u16 As[256 * 64];   // 32 KB
    __shared__ __attribute__((aligned(16))) u16 Ws[128 * 64];   // 16 KB
    const int gx = gridDim.x;
    const int nwg = gx * gridDim.y;
    const int wg = blockIdx.y * gx + blockIdx.x;
    const int nid = (wg & 7) * (nwg >> 3) + (wg >> 3);
    const int bm = (nid / gx) * 256;
    const int bn = (nid % gx) * 128;

    const int t = threadIdx.x;
    const int lane = t & 63;
    const int wave = t >> 6;
    const int wm = wave >> 2;
    const int wn = wave & 3;
    const int fr = lane & 15;
    const int fq = lane >> 4;
    const int fr7 = fr & 7;

    f32x4 acc[8][2];
#pragma unroll
    for (int m = 0; m < 8; ++m)
#pragma unroll
        for (int n = 0; n < 2; ++n) acc[m][n] = 0;

    const u16* Ag = A + (size_t)bm * K;
    const u16* Wg = W + (size_t)bn * K;

    for (int kt = 0; kt < K; kt += 64) {
#pragma unroll
        for (int q = 0; q < 4; ++q) {
            int ch = t + 512 * q;
            int row = ch >> 3, slot = ch & 7;
            gload_lds16(Ag + (size_t)row * K + kt + 8 * (slot ^ (row & 7)),
                        &As[ch * 8]);
        }
#pragma unroll
        for (int q = 0; q < 2; ++q) {
            int ch = t + 512 * q;
            int row = ch >> 3, slot = ch & 7;
            gload_lds16(Wg + (size_t)row * K + kt + 8 * (slot ^ (row & 7)),
                        &Ws[ch * 8]);
        }
        __syncthreads();
#pragma unroll
        for (int ks = 0; ks < 2; ++ks) {
            bf16x8 af[8], bw[2];
#pragma unroll
            for (int mi = 0; mi < 8; ++mi) {
                int r = wm * 128 + mi * 16 + fr;
                af[mi] = *(const bf16x8*)&As[r * 64 + ((ks * 4 + fq) ^ fr7) * 8];
            }
#pragma unroll
            for (int ni = 0; ni < 2; ++ni) {
                int r = wn * 32 + ni * 16 + fr;
                bw[ni] = *(const bf16x8*)&Ws[r * 64 + ((ks * 4 + fq) ^ fr7) * 8];
            }
#pragma unroll
            for (int mi = 0; mi < 8; ++mi)
#pragma unroll
                for (int ni = 0; ni < 2; ++ni)
                    acc[mi][ni] = __builtin_amdgcn_mfma_f32_16x16x32_bf16(
                        af[mi], bw[ni], acc[mi][ni], 0, 0, 0);
        }
        __syncthreads();
    }

#pragma unroll
    for (int m = 0; m < 8; ++m)
#pragma unroll
        for (int n = 0; n < 2; ++n) {
            int col = bn + wn * 32 + n * 16 + fr;
            if (col >= Nreal) continue;
            int row0 = bm + wm * 128 + m * 16 + fq * 4;
#pragma unroll
            for (int r = 0; r < 4; ++r)
                Cb[(size_t)(row0 + r) * Nstride + col] = f2bf(acc[m][n][r]);
        }
    if (bn + 128 > INTER + CONV_DIM) {
#pragma unroll
        for (int m = 0; m < 8; ++m)
#pragma unroll
            for (int n = 0; n < 2; ++n) {
                int col = bn + wn * 32 + n * 16 + fr;
                if (col < INTER + CONV_DIM || col >= Nreal) continue;
                int row0 = bm + wm * 128 + m * 16 + fq * 4;
#pragma unroll
                for (int r = 0; r < 4; ++r)
                    dtside[(size_t)(row0 + r) * NH +
                           (col - INTER - CONV_DIM)] = acc[m][n][r];
            }
    }
}

// ---------------------------------------------------------------------------
// out_proj GEMM — lean 128^2 tile, BK=64, split-K (z), bf16 partials.
// (R9-proven structure; only the store dtype changed, proven in R13.)
// ---------------------------------------------------------------------------
__global__ __launch_bounds__(256)
void gemm_ks_kernel(const u16* __restrict__ A, const u16* __restrict__ W,
                    u16* __restrict__ Cp, int M, int N, int Kfull, int Ksub) {
    __shared__ __attribute__((aligned(16))) u16 As[128 * 64];   // 16 KB
    __shared__ __attribute__((aligned(16))) u16 Ws[128 * 64];   // 16 KB
    const int gx = gridDim.x;
    const int nwg = gx * gridDim.y;
    const int wg = blockIdx.y * gx + blockIdx.x;
    const int nid = (wg & 7) * (nwg >> 3) + (wg >> 3);
    const int bm = (nid / gx) * 128;
    const int bn = (nid % gx) * 128;
    const int k0 = blockIdx.z * Ksub;

    const int t = threadIdx.x;
    const int lane = t & 63;
    const int wave = t >> 6;
    const int wr = wave >> 1, wc = wave & 1;
    const int fr = lane & 15;
    const int fq = lane >> 4;
    const int fr7 = fr & 7;

    f32x4 acc[4][4];
#pragma unroll
    for (int m = 0; m < 4; ++m)
#pragma unroll
        for (int n = 0; n < 4; ++n) acc[m][n] = 0;

    const u16* Ag = A + (size_t)bm * Kfull + k0;
    const u16* Wg = W + (size_t)bn * Kfull + k0;

    for (int kt = 0; kt < Ksub; kt += 64) {
#pragma unroll
        for (int q = 0; q < 4; ++q) {
            int ch = t + 256 * q;
            int row = ch >> 3, slot = ch & 7;
            int ksrc = kt + (slot ^ (row & 7)) * 8;
            gload_lds16(Ag + (size_t)row * Kfull + ksrc, &As[ch * 8]);
            gload_lds16(Wg + (size_t)row * Kfull + ksrc, &Ws[ch * 8]);
        }
        __syncthreads();
#pragma unroll
        for (int ks = 0; ks < 2; ++ks) {
            bf16x8 af[4], bw[4];
#pragma unroll
            for (int mi = 0; mi < 4; ++mi) {
                int r = wr * 64 + mi * 16 + fr;
                af[mi] = *(const bf16x8*)&As[r * 64 + ((ks * 4 + fq) ^ fr7) * 8];
            }
#pragma unroll
            for (int ni = 0; ni < 4; ++ni) {
                int r = wc * 64 + ni * 16 + fr;
                bw[ni] = *(const bf16x8*)&Ws[r * 64 + ((ks * 4 + fq) ^ fr7) * 8];
            }
#pragma unroll
            for (int mi = 0; mi < 4; ++mi)
#pragma unroll
                for (int ni = 0; ni < 4; ++ni)
                    acc[mi][ni] = __builtin_amdgcn_mfma_f32_16x16x32_bf16(
                        af[mi], bw[ni], acc[mi][ni], 0, 0, 0);
        }
        __syncthreads();
    }

    u16* Cz = Cp + (size_t)blockIdx.z * M * N;
#pragma unroll
    for (int m = 0; m < 4; ++m)
#pragma unroll
        for (int n = 0; n < 4; ++n) {
            int col = bn + wc * 64 + n * 16 + fr;
            int row0 = bm + wr * 64 + m * 16 + fq * 4;
#pragma unroll
            for (int r = 0; r < 4; ++r)
                Cz[(size_t)(row0 + r) * N + col] = f2bf(acc[m][n][r]);
        }
}

// ---------------------------------------------------------------------------
// Split-K reduce (4 bf16 partials): o[i] = p0+p1+p2+p3  (f32 out)
// ---------------------------------------------------------------------------
__global__ __launch_bounds__(256)
void addred4_kernel(const u16* __restrict__ p, float* __restrict__ o, long n) {
    long i = ((long)blockIdx.x * 256 + threadIdx.x) * 8;
    if (i >= n) return;
    u16x8 a = *(const u16x8*)&p[i];
    u16x8 b = *(const u16x8*)&p[n + i];
    u16x8 c = *(const u16x8*)&p[2 * n + i];
    u16x8 d = *(const u16x8*)&p[3 * n + i];
    float4 r0, r1;
    r0.x = bf2f(a[0]) + bf2f(b[0]) + bf2f(c[0]) + bf2f(d[0]);
    r0.y = bf2f(a[1]) + bf2f(b[1]) + bf2f(c[1]) + bf2f(d[1]);
    r0.z = bf2f(a[2]) + bf2f(b[2]) + bf2f(c[2]) + bf2f(d[2]);
    r0.w = bf2f(a[3]) + bf2f(b[3]) + bf2f(c[3]) + bf2f(d[3]);
    r1.x = bf2f(a[4]) + bf2f(b[4]) + bf2f(c[4]) + bf2f(d[4]);
    r1.y = bf2f(a[5]) + bf2f(b[5]) + bf2f(c[5]) + bf2f(d[5]);
    r1.z = bf2f(a[6]) + bf2f(b[6]) + bf2f(c[6]) + bf2f(d[6]);
    r1.w = bf2f(a[7]) + bf2f(b[7]) + bf2f(c[7]) + bf2f(d[7]);
    *(float4*)&o[i]     = r0;
    *(float4*)&o[i + 4] = r1;
}

// ---------------------------------------------------------------------------
// Fused depthwise conv(K=4)+silu + transpose/pack (bf16 zx input).
// ---------------------------------------------------------------------------
__global__ __launch_bounds__(256)
void convT_kernel(const u16* __restrict__ zxb,
                  const float* __restrict__ conv_w,
                  const float* __restrict__ conv_b,
                  u16* __restrict__ xT, u16* __restrict__ BT,
                  u16* __restrict__ Bbf, u16* __restrict__ Cbf) {
    __shared__ float s[64][65];
    const int c0 = blockIdx.x * 64;
    const int l0 = blockIdx.y * 64;
    const int b  = blockIdx.z;
    const int t  = threadIdx.x;
    const int j  = t & 63;
    const int g  = t >> 6;
    const int cg = c0 + j;
    const float w0 = conv_w[cg * 4 + 0], w1 = conv_w[cg * 4 + 1];
    const float w2 = conv_w[cg * 4 + 2], w3 = conv_w[cg * 4 + 3];
    const float bias = conv_b[cg];
    const u16* col = zxb + (size_t)b * SEQ * DPROJ + INTER + cg;
    int lbase = l0 + g * 16;
    float h3, h2, h1;
    h3 = (lbase - 3 >= 0) ? bf2f(col[(size_t)(lbase - 3) * DPROJ]) : 0.f;
    h2 = (lbase - 2 >= 0) ? bf2f(col[(size_t)(lbase - 2) * DPROJ]) : 0.f;
    h1 = (lbase - 1 >= 0) ? bf2f(col[(size_t)(lbase - 1) * DPROJ]) : 0.f;
#pragma unroll
    for (int k = 0; k < 16; ++k) {
        int l = lbase + k;
        float x0 = bf2f(col[(size_t)l * DPROJ]);
        float v = bias + h3 * w0 + h2 * w1 + h1 * w2 + x0 * w3;
        v = v / (1.f + __expf(-v));
        h3 = h2; h2 = h1; h1 = x0;
        s[g * 16 + k][j] = v;
        if (cg >= INTER) {
            int n = cg - INTER;
            if (n < STATE)
                Bbf[(size_t)(b * SEQ + l) * STATE + n] = f2bf(v);
            else
                Cbf[(size_t)(b * SEQ + l) * STATE + (n - STATE)] = f2bf(v);
        }
    }
    if (c0 >= INTER + STATE) return;
    __syncthreads();
    const int rr = t >> 2;
    const int lch = (t & 3) * 16;
    int cgout = c0 + rr;
    u16* orow;
    if (cgout < INTER) orow = xT + (size_t)(b * SEQ + cgout) * SEQ;
    else               orow = BT + (size_t)(b * STATE + (cgout - INTER)) * SEQ;
    u16x8 o0, o1;
#pragma unroll
    for (int e = 0; e < 8; ++e) o0[e] = f2bf(s[lch + e][rr]);
#pragma unroll
    for (int e = 0; e < 8; ++e) o1[e] = f2bf(s[lch + 8 + e][rr]);
    *(u16x8*)&orow[l0 + lch]     = o0;
    *(u16x8*)&orow[l0 + lch + 8] = o1;
}

// ---------------------------------------------------------------------------
// dt = softplus(dtraw + dt_bias); seg = inclusive cumsum(dt * A) per chunk.
// ---------------------------------------------------------------------------
__global__ __launch_bounds__(256)
void dtseg_kernel(const float* __restrict__ dtraw,
                  const float* __restrict__ dt_bias,
                  const float* __restrict__ A_log,
                  float* __restrict__ dt_out,
                  float* __restrict__ seg_out) {
    int bid = blockIdx.x;
    int h = bid & 31, c = (bid >> 5) & 7, b = bid >> 8;
    int i = threadIdx.x;
    int bl = b * SEQ + c * QCH + i;
    float x = dtraw[(size_t)bl * NH + h] + dt_bias[h];
    float dtv = (x > 20.f) ? x : log1pf(expf(x));
    dt_out[bl * NH + h] = dtv;
    float Ah = -expf(A_log[h]);
    __shared__ float s[QCH];
    s[i] = dtv * Ah;
    __syncthreads();
    for (int off = 1; off < QCH; off <<= 1) {
        float add = (i >= off) ? s[i - off] : 0.f;
        __syncthreads();
        s[i] += add;
        __syncthreads();
    }
    seg_out[bl * NH + h] = s[i];
}

// ---------------------------------------------------------------------------
// CB[bc,i,j] = sum_n C[i,n]*B[j,n] via MFMA -> bf16. grid (jt=4, it=4, bc=16).
// ---------------------------------------------------------------------------
__global__ __launch_bounds__(256)
void cb_kernel(const u16* __restrict__ Cbf, const u16* __restrict__ Bbf,
               u16* __restrict__ CBbf) {
    const int jt = blockIdx.x, it = blockIdx.y;
    if (jt > it) return;
    const int bc = blockIdx.z;
    const int b = bc >> 3, c = bc & 7;
    __shared__ __attribute__((aligned(16))) u16 Ct[64 * 32];
    __shared__ __attribute__((aligned(16))) u16 Bt[64 * 32];
    const int t = threadIdx.x;
    const int lane = t & 63, wave = t >> 6;
    const int wr = wave >> 1, wc = wave & 1;
    const int fr = lane & 15, fq = lane >> 4;
    const int l0 = b * SEQ + c * QCH;
    f32x4 acc[2][2];
#pragma unroll
    for (int m = 0; m < 2; ++m)
#pragma unroll
        for (int n = 0; n < 2; ++n) acc[m][n] = 0;
    const int srow = t >> 2, sslot = t & 3;
    for (int n0 = 0; n0 < STATE; n0 += 32) {
        gload_lds16(Cbf + (size_t)(l0 + it * 64 + srow) * STATE + n0 +
                        8 * (sslot ^ ((srow >> 1) & 3)), &Ct[t * 8]);
        gload_lds16(Bbf + (size_t)(l0 + jt * 64 + srow) * STATE + n0 +
                        8 * (sslot ^ ((srow >> 1) & 3)), &Bt[t * 8]);
        __syncthreads();
        bf16x8 af[2], bw[2];
#pragma unroll
        for (int m = 0; m < 2; ++m)
            af[m] = *(const bf16x8*)&Ct[swz64(wr * 32 + m * 16 + fr, fq)];
#pragma unroll
        for (int n = 0; n < 2; ++n)
            bw[n] = *(const bf16x8*)&Bt[swz64(wc * 32 + n * 16 + fr, fq)];
#pragma unroll
        for (int m = 0; m < 2; ++m)
#pragma unroll
            for (int n = 0; n < 2; ++n)
                acc[m][n] = __builtin_amdgcn_mfma_f32_16x16x32_bf16(
                    af[m], bw[n], acc[m][n], 0, 0, 0);
        __syncthreads();
    }
#pragma unroll
    for (int m = 0; m < 2; ++m)
#pragma unroll
        for (int n = 0; n < 2; ++n) {
            int i = it * 64 + wr * 32 + m * 16 + fq * 4;
            int jj = jt * 64 + wc * 32 + n * 16 + fr;
#pragma unroll
            for (int r = 0; r < 4; ++r)
                CBbf[((size_t)bc * QCH + i + r) * QCH + jj] = f2bf(acc[m][n][r]);
        }
}

// ---------------------------------------------------------------------------
// states[b,c,h,p,n] = sum_j x[j,p]*dt[j]*exp(seg_last-seg[j]) * B[j,n]
// BK=64 j-tiles, swz128 (R11/R12, passing).
// ---------------------------------------------------------------------------
__global__ __launch_bounds__(256)
void states_kernel(const u16* __restrict__ xT, const u16* __restrict__ BT,
                   const float* __restrict__ dt, const float* __restrict__ seg,
                   u16* __restrict__ statesb) {
    int bid = blockIdx.x;
    int h = bid & 31, c = (bid >> 5) & 7, b = bid >> 8;
    __shared__ float dd[QCH];
    __shared__ __attribute__((aligned(16))) u16 At[64 * 64];    //  8 KB
    __shared__ __attribute__((aligned(16))) u16 Bt[128 * 64];   // 16 KB
    const int t = threadIdx.x;
    const int lane = t & 63, wave = t >> 6;
    const int wr = wave >> 1, wc = wave & 1;
    const int fr = lane & 15, fq = lane >> 4;
    const int fr7 = fr & 7;
    const int l0 = b * SEQ + c * QCH;
    {
        float seg_last = seg[(size_t)(l0 + QCH - 1) * NH + h];
        dd[t] = dt[(size_t)(l0 + t) * NH + h] *
                __expf(seg_last - seg[(size_t)(l0 + t) * NH + h]);
    }
    __syncthreads();
    f32x4 acc[2][4];
#pragma unroll
    for (int m = 0; m < 2; ++m)
#pragma unroll
        for (int n = 0; n < 4; ++n) acc[m][n] = 0;

    for (int j0 = 0; j0 < QCH; j0 += 64) {
#pragma unroll
        for (int q = 0; q < 2; ++q) {
            int ch = t + 256 * q;
            int row = ch >> 3, slot = ch & 7;
            u16x8 v = *(const u16x8*)&xT[(size_t)(b * SEQ + h * PDIM + row) * SEQ +
                                         c * QCH + j0 + slot * 8];
            u16x8 o;
#pragma unroll
            for (int e = 0; e < 8; ++e)
                o[e] = f2bf(bf2f(v[e]) * dd[j0 + slot * 8 + e]);
            *(u16x8*)&At[swz128(row, slot)] = o;
        }
#pragma unroll
        for (int q = 0; q < 4; ++q) {
            int ch = t + 256 * q;
            int row = ch >> 3, slot = ch & 7;
            gload_lds16(BT + (size_t)(b * STATE + row) * SEQ + c * QCH + j0 +
                            8 * (slot ^ (row & 7)), &Bt[ch * 8]);
        }
        __syncthreads();
#pragma unroll
        for (int ks = 0; ks < 2; ++ks) {
            bf16x8 af[2], bw[4];
#pragma unroll
            for (int m = 0; m < 2; ++m) {
                int r = wr * 32 + m * 16 + fr;
                af[m] = *(const bf16x8*)&At[r * 64 + ((ks * 4 + fq) ^ fr7) * 8];
            }
#pragma unroll
            for (int n = 0; n < 4; ++n) {
                int r = wc * 64 + n * 16 + fr;
                bw[n] = *(const bf16x8*)&Bt[r * 64 + ((ks * 4 + fq) ^ fr7) * 8];
            }
#pragma unroll
            for (int m = 0; m < 2; ++m)
#pragma unroll
                for (int n = 0; n < 4; ++n)
                    acc[m][n] = __builtin_amdgcn_mfma_f32_16x16x32_bf16(
                        af[m], bw[n], acc[m][n], 0, 0, 0);
        }
        __syncthreads();
    }
    size_t base = ((((size_t)b * NCHUNK + c) * NH + h) * PDIM) * STATE;
#pragma unroll
    for (int m = 0; m < 2; ++m)
#pragma unroll
        for (int n = 0; n < 4; ++n) {
            int p = wr * 32 + m * 16 + fq * 4;
            int nn = wc * 64 + n * 16 + fr;
#pragma unroll
            for (int r = 0; r < 4; ++r)
                statesb[base + (size_t)(p + r) * STATE + nn] = f2bf(acc[m][n][r]);
        }
}

// ---------------------------------------------------------------------------
// Inter-chunk scan: reads bf16 states, f32 carry, writes bf16 prev only.
// ---------------------------------------------------------------------------
__global__ void scan_kernel(const u16* __restrict__ statesb,
                            const float* __restrict__ seg,
                            u16* __restrict__ prevbf) {
    int tid = blockIdx.x * blockDim.x + threadIdx.x;
    int n = tid & 127, p = (tid >> 7) & 63, h = (tid >> 13) & 31, b = tid >> 18;
    float carry = 0.f;
    for (int c = 0; c < NCHUNK; ++c) {
        size_t idx = ((((size_t)b * NCHUNK + c) * NH + h) * PDIM + p) * STATE + n;
        float st = bf2f(statesb[idx]);
        prevbf[idx] = f2bf(carry);
        float dec = __expf(seg[(size_t)(b*SEQ + c*QCH + QCH - 1) * NH + h]);
        carry = carry * dec + st;
    }
}

// ---------------------------------------------------------------------------
// Fused Yo + Yd (+ D*x via M-diagonal) -> y (bf16).  (R11/R12, passing)
// ---------------------------------------------------------------------------
__global__ __launch_bounds__(256)
void ydo_kernel(const u16* __restrict__ xT, const u16* __restrict__ Cbf,
                const u16* __restrict__ prevbf, const u16* __restrict__ CBbf,
                const float* __restrict__ dt, const float* __restrict__ seg,
                const float* __restrict__ Dv, u16* __restrict__ yb) {
    int bid = blockIdx.x;
    int h = bid & 31, c = (bid >> 5) & 7, b = bid >> 8;
    __shared__ float seg_s[QCH], sge_s[QCH], dtv_s[QCH];
    __shared__ __attribute__((aligned(16))) u16 big[QCH * 64];   // 32 KB
    __shared__ __attribute__((aligned(16))) u16 small[64 * 64];  // 8 KB
    const int t = threadIdx.x;
    const int lane = t & 63, w = t >> 6;
    const int fr = lane & 15, fq = lane >> 4;
    const int l0 = b * SEQ + c * QCH;
    const float Dh = Dv[h];
    {
        float sv = seg[(size_t)(l0 + t) * NH + h];
        seg_s[t] = sv;
        sge_s[t] = __expf(sv);
        dtv_s[t] = dt[(size_t)(l0 + t) * NH + h];
    }
    __syncthreads();
    f32x4 acc[4][4];
#pragma unroll
    for (int m = 0; m < 4; ++m)
#pragma unroll
        for (int n = 0; n < 4; ++n) acc[m][n] = 0;

    const size_t pvbase = ((((size_t)b * NCHUNK + c) * NH + h) * PDIM) * STATE;
    for (int kc = 0; kc < 2; ++kc) {
#pragma unroll
        for (int q = 0; q < 8; ++q) {
            int ch = t + 256 * q;
            int row = ch >> 3, slot = ch & 7;
            gload_lds16(Cbf + (size_t)(l0 + row) * STATE + kc * 64 +
                            8 * (slot ^ (row & 7)), &big[ch * 8]);
        }
#pragma unroll
        for (int q = 0; q < 2; ++q) {
            int ch = t + 256 * q;
            int row = ch >> 3, slot = ch & 7;
            gload_lds16(prevbf + pvbase + (size_t)row * STATE + kc * 64 +
                            8 * (slot ^ (row & 7)), &small[ch * 8]);
        }
        __syncthreads();
#pragma unroll
        for (int ks2 = 0; ks2 < 2; ++ks2) {
            bf16x8 af[4], bw[4];
#pragma unroll
            for (int m = 0; m < 4; ++m)
                af[m] = *(const bf16x8*)&big[swz128(64 * m + 16 * w + fr,
                                                   ks2 * 4 + fq)];
#pragma unroll
            for (int n = 0; n < 4; ++n)
                bw[n] = *(const bf16x8*)&small[swz128(16 * n + fr,
                                                      ks2 * 4 + fq)];
#pragma unroll
            for (int m = 0; m < 4; ++m)
#pragma unroll
                for (int n = 0; n < 4; ++n)
                    acc[m][n] = __builtin_amdgcn_mfma_f32_16x16x32_bf16(
                        af[m], bw[n], acc[m][n], 0, 0, 0);
        }
        __syncthreads();
    }
#pragma unroll
    for (int m = 0; m < 4; ++m)
#pragma unroll
        for (int n = 0; n < 4; ++n)
#pragma unroll
            for (int r = 0; r < 4; ++r)
                acc[m][n][r] *= sge_s[64 * m + 16 * w + fq * 4 + r];

    const u16* CBrow = CBbf + (size_t)(b * NCHUNK + c) * QCH * QCH;
    for (int jt = 0; jt < 4; ++jt) {
        const int j0 = jt * 64;
        const int c4 = (t & 15) * 4;
        for (int r = j0 + (t >> 4); r < QCH; r += 16) {
            u16x4 cb4 = *(const u16x4*)&CBrow[(size_t)r * QCH + j0 + c4];
            u16x4 o4;
            int d = r - j0;
#pragma unroll
            for (int e = 0; e < 4; ++e) {
                int mcol = c4 + e;
                float v = 0.f;
                if (mcol <= d) {
                    v = bf2f(cb4[e]) * __expf(seg_s[r] - seg_s[j0 + mcol]) *
                        dtv_s[j0 + mcol];
                    if (mcol == d) v += Dh;
                }
                o4[e] = f2bf(v);
            }
            *(u16x4*)&big[((r * 128 + c4 * 2) ^ ((r & 7) << 4)) >> 1] = o4;
        }
#pragma unroll
        for (int q = 0; q < 2; ++q) {
            int chunk = t + 256 * q;
            int row = chunk >> 3, slot = chunk & 7;
            gload_lds16(xT + (size_t)(b * SEQ + h * PDIM + row) * SEQ +
                            c * QCH + j0 + 8 * (slot ^ (row & 7)),
                        &small[chunk * 8]);
        }
        __syncthreads();
#pragma unroll
        for (int ks = 0; ks < 2; ++ks) {
#pragma unroll
            for (int m = 0; m < 4; ++m) {
                if (64 * m + 16 * w >= j0) {
                    bf16x8 af = *(const bf16x8*)
                        &big[swz128(64 * m + 16 * w + fr, ks * 4 + fq)];
#pragma unroll
                    for (int n = 0; n < 4; ++n) {
                        bf16x8 bw = *(const bf16x8*)
                            &small[swz128(16 * n + fr, ks * 4 + fq)];
                        acc[m][n] = __builtin_amdgcn_mfma_f32_16x16x32_bf16(
                            af, bw, acc[m][n], 0, 0, 0);
                    }
                }
            }
        }
        __syncthreads();
    }
#pragma unroll
    for (int m = 0; m < 4; ++m) {
        int i = 64 * m + 16 * w + fq * 4;
#pragma unroll
        for (int n = 0; n < 4; ++n) {
            int p = 16 * n + fr;
#pragma unroll
            for (int r = 0; r < 4; ++r)
                yb[(size_t)(l0 + i + r) * INTER + h * PDIM + p] =
                    f2bf(acc[m][n][r]);
        }
    }
}

// ---------------------------------------------------------------------------
// yg = y * silu(z); RMS-norm; * norm_weight.  In place on bf16 y.
// ---------------------------------------------------------------------------
__global__ __launch_bounds__(256)
void gatenorm_kernel(u16* __restrict__ yb, const u16* __restrict__ zxb,
                     const float* __restrict__ nw) {
    int bl = blockIdx.x;
    int t = threadIdx.x;
    u16x8 yv8 = *(const u16x8*)&yb[(size_t)bl * INTER + t * 8];
    u16x8 zv8 = *(const u16x8*)&zxb[(size_t)bl * DPROJ + t * 8];
    float g[8];
    float ss = 0.f;
#pragma unroll
    for (int i = 0; i < 8; ++i) {
        float yv = bf2f(yv8[i]), zv = bf2f(zv8[i]);
        g[i] = yv * (zv / (1.f + __expf(-zv)));
        ss += g[i] * g[i];
    }
    for (int off = 32; off > 0; off >>= 1) ss += __shfl_xor(ss, off, 64);
    __shared__ float red[4];
    if ((t & 63) == 0) red[t >> 6] = ss;
    __syncthreads();
    float tot = red[0] + red[1] + red[2] + red[3];
    float scale = rsqrtf(tot / INTER + 1e-6f);
    const float* nwp = nw + t * 8;
    u16x8 o;
#pragma unroll
    for (int i = 0; i < 8; ++i) o[i] = f2bf(g[i] * scale * nwp[i]);
    *(u16x8*)&yb[(size_t)bl * INTER + t * 8] = o;
}

// ---------------------------------------------------------------------------
extern "C" void kernel_launch(void* const* d_in, const int* in_sizes, int n_in,
                              void* d_out, int out_size, void* d_ws, size_t ws_size,
                              hipStream_t stream) {
    const float* hidden     = (const float*)d_in[0];
    const float* in_proj_w  = (const float*)d_in[1];
    const float* conv_w     = (const float*)d_in[2];
    const float* conv_b     = (const float*)d_in[3];
    const float* dt_bias    = (const float*)d_in[4];
    const float* A_log      = (const float*)d_in[5];
    const float* Dv         = (const float*)d_in[6];
    const float* norm_w     = (const float*)d_in[7];
    const float* out_proj_w = (const float*)d_in[8];
    float* out = (float*)d_out;

    // layout (u16 units unless noted) — identical to round 12 (passing)
    u16* wsu    = (u16*)d_ws;
    u16* zxb    = wsu;                                        // 17,956,864
    u16* statesb= zxb    + (size_t)BL * DPROJ;                // 16,777,216
    u16* prevbf = statesb+ (size_t)BATCH*NCHUNK*NH*PDIM*STATE;// 16,777,216
    u16* yb     = prevbf + (size_t)BATCH*NCHUNK*NH*PDIM*STATE;//  8,388,608
    u16* xT     = yb     + (size_t)BL * INTER;                //  8,388,608
    u16* BT     = xT     + (size_t)BL * INTER;                //    524,288
    u16* Bbf    = BT     + (size_t)BATCH * STATE * SEQ;       //    524,288
    u16* Cbf    = Bbf    + (size_t)BL * STATE;                //    524,288
    u16* W2bf   = Cbf    + (size_t)BL * STATE;                //  2,097,152
    float* dtraw = (float*)(W2bf + (size_t)HID * INTER);      //    131,072 f32
    float* dtb   = dtraw + (size_t)BL * NH;                   //    131,072 f32
    float* segb  = dtb   + (size_t)BL * NH;                   //    131,072 f32
    u16*  CBbf   = (u16*)(segb + (size_t)BL * NH);            //  1,048,576 u16
    // aliases into dead regions:
    u16* Abf = statesb;                       // dead once in_proj GEMM done
    u16* Wbf = statesb + (size_t)BL * HID;
    // bf16 kpart: 4 partials x BL*HID u16 = 33.6 MB, fits entirely inside
    // zxb (35.9 MB, dead after gatenorm).
    u16* kpart = zxb;

    // 1. fused f32->bf16 conversions
    {
        long total = (long)BL*HID + (long)DPROJ_PAD*HID + (long)HID*INTER;
        cvt_all<<<(int)(total / 2048), 256, 0, stream>>>(
            hidden, in_proj_w, out_proj_w, Abf, Wbf, W2bf);
    }

    // 2. in_proj: zxb(bf16) = Abf @ Wbf^T, dt cols also f32 -> dtraw
    gemm_in_kernel<<<dim3(DPROJ_PAD/128, BL/256), 512, 0, stream>>>(
        Abf, Wbf, zxb, dtraw, DPROJ, DPROJ, HID);

    dtseg_kernel<<<BATCH * NCHUNK * NH, 256, 0, stream>>>(
        dtraw, dt_bias, A_log, dtb, segb);
    convT_kernel<<<dim3(CONV_DIM/64, SEQ/64, BATCH), 256, 0, stream>>>(
        zxb, conv_w, conv_b, xT, BT, Bbf, Cbf);
    cb_kernel<<<dim3(4, 4, BATCH*NCHUNK), 256, 0, stream>>>(Cbf, Bbf, CBbf);
    states_kernel<<<BATCH * NCHUNK * NH, 256, 0, stream>>>(
        xT, BT, dtb, segb, statesb);
    scan_kernel<<<(BATCH * NH * PDIM * STATE) / 256, 256, 0, stream>>>(
        statesb, segb, prevbf);
    ydo_kernel<<<BATCH * NCHUNK * NH, 256, 0, stream>>>(
        xT, Cbf, prevbf, CBbf, dtb, segb, Dv, yb);
    gatenorm_kernel<<<BL, 256, 0, stream>>>(yb, zxb, norm_w);

    // out_proj: 128^2 tile, split-K=4, bf16 partials; then 4-way reduce
    gemm_ks_kernel<<<dim3(HID/128, BL/128, 4), 256, 0, stream>>>(
        yb, W2bf, kpart, BL, HID, INTER, INTER/4);
    addred4_kernel<<<((long)BL*HID)/2048, 256, 0, stream>>>(
        kpart, out, (long)BL*HID);
}

// Round 15
// 187.261 us; speedup vs baseline: 1.0142x; 1.0142x over previous
//
#include <hip/hip_runtime.h>

#define HID      1024
#define INTER    2048
#define STATE    128
#define NH       32
#define PDIM     64
#define KCONV    4
#define QCH      256
#define CONV_DIM (INTER + 2*STATE)      // 2304
#define DPROJ    (2*INTER + 2*STATE + NH) // 4384
#define DPROJ_PAD 4480                  // next multiple of 128
#define BATCH    2
#define SEQ      2048
#define NCHUNK   (SEQ / QCH)            // 8
#define BL       (BATCH * SEQ)          // 4096

typedef unsigned short u16;
typedef unsigned int   u32;
typedef u16 u16x8 __attribute__((ext_vector_type(8)));
typedef u16 u16x4 __attribute__((ext_vector_type(4)));
typedef float f32x4 __attribute__((ext_vector_type(4)));
typedef __bf16 bf16x8 __attribute__((ext_vector_type(8)));

static __device__ __forceinline__ u16 f2bf(float f) {
    u32 u = __float_as_uint(f);
    return (u16)((u + 0x7FFFu + ((u >> 16) & 1u)) >> 16);
}
static __device__ __forceinline__ float bf2f(u16 v) {
    return __uint_as_float(((u32)v) << 16);
}
static __device__ __forceinline__ void gload_lds16(const void* g, void* l) {
    __builtin_amdgcn_global_load_lds(
        (const __attribute__((address_space(1))) void*)g,
        (__attribute__((address_space(3))) void*)l, 16, 0, 0);
}
// swizzled LDS u16-index helpers (row-major tiles; byte XOR at 16B granularity)
static __device__ __forceinline__ int swz64(int row, int slot) {   // 64B rows
    return ((row * 64 + slot * 16) ^ (((row >> 1) & 3) << 4)) >> 1;
}
static __device__ __forceinline__ int swz128(int row, int slot) {  // 128B rows
    return ((row * 128 + slot * 16) ^ ((row & 7) << 4)) >> 1;
}

// ---------------------------------------------------------------------------
// Fused f32 -> bf16 conversion of hidden + in_proj_w (padded) + out_proj_w.
// ---------------------------------------------------------------------------
__global__ __launch_bounds__(256)
void cvt_all(const float* __restrict__ hidden, const float* __restrict__ w1,
             const float* __restrict__ w2, u16* __restrict__ Abf,
             u16* __restrict__ Wbf, u16* __restrict__ W2bf) {
    const long nA  = (long)BL * HID;
    const long nW  = (long)DPROJ_PAD * HID;
    const long nWr = (long)DPROJ * HID;
    const long nW2 = (long)HID * INTER;
    long i = ((long)blockIdx.x * 256 + threadIdx.x) * 8;
    const float* src; u16* dst; long j;
    if (i < nA)            { src = hidden; dst = Abf;  j = i; }
    else if (i < nA + nW)  { j = i - nA;
        if (j >= nWr) { *(u16x8*)&Wbf[j] = (u16x8)0; return; }
        src = w1; dst = Wbf; }
    else                   { j = i - nA - nW;
        if (j >= nW2) return;
        src = w2; dst = W2bf; }
    float4 a = *(const float4*)&src[j];
    float4 b = *(const float4*)&src[j + 4];
    u16x8 o;
    o[0] = f2bf(a.x); o[1] = f2bf(a.y); o[2] = f2bf(a.z); o[3] = f2bf(a.w);
    o[4] = f2bf(b.x); o[5] = f2bf(b.y); o[6] = f2bf(b.z); o[7] = f2bf(b.w);
    *(u16x8*)&dst[j] = o;
}

// ---------------------------------------------------------------------------
// in_proj GEMM — BM=256 x BN=128, 8 waves, BK=64, 2-phase (R12, passing).
// ---------------------------------------------------------------------------
__global__ __launch_bounds__(512)
void gemm_in_kernel(const u16* __restrict__ A, const u16* __restrict__ W,
                    u16* __restrict__ Cb, float* __restrict__ dtside,
                    int Nstride, int Nreal, int K) {
    __shared__ __attribute__((aligned(16))) u16 As[256 * 64];   // 32 KB
    __shared__ __attribute__((aligned(16))) u16 Ws[128 * 64];   // 16 KB
    const int gx = gridDim.x;
    const int nwg = gx * gridDim.y;
    const int wg = blockIdx.y * gx + blockIdx.x;
    const int nid = (wg & 7) * (nwg >> 3) + (wg >> 3);
    const int bm = (nid / gx) * 256;
    const int bn = (nid % gx) * 128;

    const int t = threadIdx.x;
    const int lane = t & 63;
    const int wave = t >> 6;
    const int wm = wave >> 2;
    const int wn = wave & 3;
    const int fr = lane & 15;
    const int fq = lane >> 4;
    const int fr7 = fr & 7;

    f32x4 acc[8][2];
#pragma unroll
    for (int m = 0; m < 8; ++m)
#pragma unroll
        for (int n = 0; n < 2; ++n) acc[m][n] = 0;

    const u16* Ag = A + (size_t)bm * K;
    const u16* Wg = W + (size_t)bn * K;

    for (int kt = 0; kt < K; kt += 64) {
#pragma unroll
        for (int q = 0; q < 4; ++q) {
            int ch = t + 512 * q;
            int row = ch >> 3, slot = ch & 7;
            gload_lds16(Ag + (size_t)row * K + kt + 8 * (slot ^ (row & 7)),
                        &As[ch * 8]);
        }
#pragma unroll
        for (int q = 0; q < 2; ++q) {
            int ch = t + 512 * q;
            int row = ch >> 3, slot = ch & 7;
            gload_lds16(Wg + (size_t)row * K + kt + 8 * (slot ^ (row & 7)),
                        &Ws[ch * 8]);
        }
        __syncthreads();
#pragma unroll
        for (int ks = 0; ks < 2; ++ks) {
            bf16x8 af[8], bw[2];
#pragma unroll
            for (int mi = 0; mi < 8; ++mi) {
                int r = wm * 128 + mi * 16 + fr;
                af[mi] = *(const bf16x8*)&As[r * 64 + ((ks * 4 + fq) ^ fr7) * 8];
            }
#pragma unroll
            for (int ni = 0; ni < 2; ++ni) {
                int r = wn * 32 + ni * 16 + fr;
                bw[ni] = *(const bf16x8*)&Ws[r * 64 + ((ks * 4 + fq) ^ fr7) * 8];
            }
#pragma unroll
            for (int mi = 0; mi < 8; ++mi)
#pragma unroll
                for (int ni = 0; ni < 2; ++ni)
                    acc[mi][ni] = __builtin_amdgcn_mfma_f32_16x16x32_bf16(
                        af[mi], bw[ni], acc[mi][ni], 0, 0, 0);
        }
        __syncthreads();
    }

#pragma unroll
    for (int m = 0; m < 8; ++m)
#pragma unroll
        for (int n = 0; n < 2; ++n) {
            int col = bn + wn * 32 + n * 16 + fr;
            if (col >= Nreal) continue;
            int row0 = bm + wm * 128 + m * 16 + fq * 4;
#pragma unroll
            for (int r = 0; r < 4; ++r)
                Cb[(size_t)(row0 + r) * Nstride + col] = f2bf(acc[m][n][r]);
        }
    if (bn + 128 > INTER + CONV_DIM) {
#pragma unroll
        for (int m = 0; m < 8; ++m)
#pragma unroll
            for (int n = 0; n < 2; ++n) {
                int col = bn + wn * 32 + n * 16 + fr;
                if (col < INTER + CONV_DIM || col >= Nreal) continue;
                int row0 = bm + wm * 128 + m * 16 + fq * 4;
#pragma unroll
                for (int r = 0; r < 4; ++r)
                    dtside[(size_t)(row0 + r) * NH +
                           (col - INTER - CONV_DIM)] = acc[m][n][r];
            }
    }
}

// ---------------------------------------------------------------------------
// out_proj GEMM — lean 128^2 tile, BK=64, split-K=2, f32 partials (R12).
// ---------------------------------------------------------------------------
__global__ __launch_bounds__(256)
void gemm_ks_kernel(const u16* __restrict__ A, const u16* __restrict__ W,
                    float* __restrict__ Cp, int M, int N, int Kfull, int Ksub) {
    __shared__ __attribute__((aligned(16))) u16 As[128 * 64];   // 16 KB
    __shared__ __attribute__((aligned(16))) u16 Ws[128 * 64];   // 16 KB
    const int gx = gridDim.x;
    const int nwg = gx * gridDim.y;
    const int wg = blockIdx.y * gx + blockIdx.x;
    const int nid = (wg & 7) * (nwg >> 3) + (wg >> 3);
    const int bm = (nid / gx) * 128;
    const int bn = (nid % gx) * 128;
    const int k0 = blockIdx.z * Ksub;

    const int t = threadIdx.x;
    const int lane = t & 63;
    const int wave = t >> 6;
    const int wr = wave >> 1, wc = wave & 1;
    const int fr = lane & 15;
    const int fq = lane >> 4;
    const int fr7 = fr & 7;

    f32x4 acc[4][4];
#pragma unroll
    for (int m = 0; m < 4; ++m)
#pragma unroll
        for (int n = 0; n < 4; ++n) acc[m][n] = 0;

    const u16* Ag = A + (size_t)bm * Kfull + k0;
    const u16* Wg = W + (size_t)bn * Kfull + k0;

    for (int kt = 0; kt < Ksub; kt += 64) {
#pragma unroll
        for (int q = 0; q < 4; ++q) {
            int ch = t + 256 * q;
            int row = ch >> 3, slot = ch & 7;
            int ksrc = kt + (slot ^ (row & 7)) * 8;
            gload_lds16(Ag + (size_t)row * Kfull + ksrc, &As[ch * 8]);
            gload_lds16(Wg + (size_t)row * Kfull + ksrc, &Ws[ch * 8]);
        }
        __syncthreads();
#pragma unroll
        for (int ks = 0; ks < 2; ++ks) {
            bf16x8 af[4], bw[4];
#pragma unroll
            for (int mi = 0; mi < 4; ++mi) {
                int r = wr * 64 + mi * 16 + fr;
                af[mi] = *(const bf16x8*)&As[r * 64 + ((ks * 4 + fq) ^ fr7) * 8];
            }
#pragma unroll
            for (int ni = 0; ni < 4; ++ni) {
                int r = wc * 64 + ni * 16 + fr;
                bw[ni] = *(const bf16x8*)&Ws[r * 64 + ((ks * 4 + fq) ^ fr7) * 8];
            }
#pragma unroll
            for (int mi = 0; mi < 4; ++mi)
#pragma unroll
                for (int ni = 0; ni < 4; ++ni)
                    acc[mi][ni] = __builtin_amdgcn_mfma_f32_16x16x32_bf16(
                        af[mi], bw[ni], acc[mi][ni], 0, 0, 0);
        }
        __syncthreads();
    }

    float* Cz = Cp + (size_t)blockIdx.z * M * N;
#pragma unroll
    for (int m = 0; m < 4; ++m)
#pragma unroll
        for (int n = 0; n < 4; ++n) {
            int col = bn + wc * 64 + n * 16 + fr;
            int row0 = bm + wr * 64 + m * 16 + fq * 4;
#pragma unroll
            for (int r = 0; r < 4; ++r)
                Cz[(size_t)(row0 + r) * N + col] = acc[m][n][r];
        }
}

// ---------------------------------------------------------------------------
// Split-K reduce (2 f32 partials): o[i] = p[i] + p[n+i]  (f32x4)
// ---------------------------------------------------------------------------
__global__ __launch_bounds__(256)
void addred_kernel(const float* __restrict__ p, float* __restrict__ o, long n) {
    long i = ((long)blockIdx.x * 256 + threadIdx.x) * 4;
    if (i >= n) return;
    float4 a = *(const float4*)&p[i];
    float4 b = *(const float4*)&p[n + i];
    float4 r = make_float4(a.x + b.x, a.y + b.y, a.z + b.z, a.w + b.w);
    *(float4*)&o[i] = r;
}

// ---------------------------------------------------------------------------
// Fused depthwise conv(K=4)+silu + transpose/pack (bf16 zx input).
// ---------------------------------------------------------------------------
__global__ __launch_bounds__(256)
void convT_kernel(const u16* __restrict__ zxb,
                  const float* __restrict__ conv_w,
                  const float* __restrict__ conv_b,
                  u16* __restrict__ xT, u16* __restrict__ BT,
                  u16* __restrict__ Bbf, u16* __restrict__ Cbf) {
    __shared__ float s[64][65];
    const int c0 = blockIdx.x * 64;
    const int l0 = blockIdx.y * 64;
    const int b  = blockIdx.z;
    const int t  = threadIdx.x;
    const int j  = t & 63;
    const int g  = t >> 6;
    const int cg = c0 + j;
    const float w0 = conv_w[cg * 4 + 0], w1 = conv_w[cg * 4 + 1];
    const float w2 = conv_w[cg * 4 + 2], w3 = conv_w[cg * 4 + 3];
    const float bias = conv_b[cg];
    const u16* col = zxb + (size_t)b * SEQ * DPROJ + INTER + cg;
    int lbase = l0 + g * 16;
    float h3, h2, h1;
    h3 = (lbase - 3 >= 0) ? bf2f(col[(size_t)(lbase - 3) * DPROJ]) : 0.f;
    h2 = (lbase - 2 >= 0) ? bf2f(col[(size_t)(lbase - 2) * DPROJ]) : 0.f;
    h1 = (lbase - 1 >= 0) ? bf2f(col[(size_t)(lbase - 1) * DPROJ]) : 0.f;
#pragma unroll
    for (int k = 0; k < 16; ++k) {
        int l = lbase + k;
        float x0 = bf2f(col[(size_t)l * DPROJ]);
        float v = bias + h3 * w0 + h2 * w1 + h1 * w2 + x0 * w3;
        v = v / (1.f + __expf(-v));
        h3 = h2; h2 = h1; h1 = x0;
        s[g * 16 + k][j] = v;
        if (cg >= INTER) {
            int n = cg - INTER;
            if (n < STATE)
                Bbf[(size_t)(b * SEQ + l) * STATE + n] = f2bf(v);
            else
                Cbf[(size_t)(b * SEQ + l) * STATE + (n - STATE)] = f2bf(v);
        }
    }
    if (c0 >= INTER + STATE) return;
    __syncthreads();
    const int rr = t >> 2;
    const int lch = (t & 3) * 16;
    int cgout = c0 + rr;
    u16* orow;
    if (cgout < INTER) orow = xT + (size_t)(b * SEQ + cgout) * SEQ;
    else               orow = BT + (size_t)(b * STATE + (cgout - INTER)) * SEQ;
    u16x8 o0, o1;
#pragma unroll
    for (int e = 0; e < 8; ++e) o0[e] = f2bf(s[lch + e][rr]);
#pragma unroll
    for (int e = 0; e < 8; ++e) o1[e] = f2bf(s[lch + 8 + e][rr]);
    *(u16x8*)&orow[l0 + lch]     = o0;
    *(u16x8*)&orow[l0 + lch + 8] = o1;
}

// ---------------------------------------------------------------------------
// dt = softplus(dtraw + dt_bias); seg = inclusive cumsum(dt * A) per chunk.
// ---------------------------------------------------------------------------
__global__ __launch_bounds__(256)
void dtseg_kernel(const float* __restrict__ dtraw,
                  const float* __restrict__ dt_bias,
                  const float* __restrict__ A_log,
                  float* __restrict__ dt_out,
                  float* __restrict__ seg_out) {
    int bid = blockIdx.x;
    int h = bid & 31, c = (bid >> 5) & 7, b = bid >> 8;
    int i = threadIdx.x;
    int bl = b * SEQ + c * QCH + i;
    float x = dtraw[(size_t)bl * NH + h] + dt_bias[h];
    float dtv = (x > 20.f) ? x : log1pf(expf(x));
    dt_out[bl * NH + h] = dtv;
    float Ah = -expf(A_log[h]);
    __shared__ float s[QCH];
    s[i] = dtv * Ah;
    __syncthreads();
    for (int off = 1; off < QCH; off <<= 1) {
        float add = (i >= off) ? s[i - off] : 0.f;
        __syncthreads();
        s[i] += add;
        __syncthreads();
    }
    seg_out[bl * NH + h] = s[i];
}

// ---------------------------------------------------------------------------
// CB[bc,i,j] = sum_n C[i,n]*B[j,n] via MFMA -> bf16. grid (jt=4, it=4, bc=16).
// ---------------------------------------------------------------------------
__global__ __launch_bounds__(256)
void cb_kernel(const u16* __restrict__ Cbf, const u16* __restrict__ Bbf,
               u16* __restrict__ CBbf) {
    const int jt = blockIdx.x, it = blockIdx.y;
    if (jt > it) return;
    const int bc = blockIdx.z;
    const int b = bc >> 3, c = bc & 7;
    __shared__ __attribute__((aligned(16))) u16 Ct[64 * 32];
    __shared__ __attribute__((aligned(16))) u16 Bt[64 * 32];
    const int t = threadIdx.x;
    const int lane = t & 63, wave = t >> 6;
    const int wr = wave >> 1, wc = wave & 1;
    const int fr = lane & 15, fq = lane >> 4;
    const int l0 = b * SEQ + c * QCH;
    f32x4 acc[2][2];
#pragma unroll
    for (int m = 0; m < 2; ++m)
#pragma unroll
        for (int n = 0; n < 2; ++n) acc[m][n] = 0;
    const int srow = t >> 2, sslot = t & 3;
    for (int n0 = 0; n0 < STATE; n0 += 32) {
        gload_lds16(Cbf + (size_t)(l0 + it * 64 + srow) * STATE + n0 +
                        8 * (sslot ^ ((srow >> 1) & 3)), &Ct[t * 8]);
        gload_lds16(Bbf + (size_t)(l0 + jt * 64 + srow) * STATE + n0 +
                        8 * (sslot ^ ((srow >> 1) & 3)), &Bt[t * 8]);
        __syncthreads();
        bf16x8 af[2], bw[2];
#pragma unroll
        for (int m = 0; m < 2; ++m)
            af[m] = *(const bf16x8*)&Ct[swz64(wr * 32 + m * 16 + fr, fq)];
#pragma unroll
        for (int n = 0; n < 2; ++n)
            bw[n] = *(const bf16x8*)&Bt[swz64(wc * 32 + n * 16 + fr, fq)];
#pragma unroll
        for (int m = 0; m < 2; ++m)
#pragma unroll
            for (int n = 0; n < 2; ++n)
                acc[m][n] = __builtin_amdgcn_mfma_f32_16x16x32_bf16(
                    af[m], bw[n], acc[m][n], 0, 0, 0);
        __syncthreads();
    }
#pragma unroll
    for (int m = 0; m < 2; ++m)
#pragma unroll
        for (int n = 0; n < 2; ++n) {
            int i = it * 64 + wr * 32 + m * 16 + fq * 4;
            int jj = jt * 64 + wc * 32 + n * 16 + fr;
#pragma unroll
            for (int r = 0; r < 4; ++r)
                CBbf[((size_t)bc * QCH + i + r) * QCH + jj] = f2bf(acc[m][n][r]);
        }
}

// ---------------------------------------------------------------------------
// states[b,c,h,p,n] = sum_j x[j,p]*dt[j]*exp(seg_last-seg[j]) * B[j,n]
// BK=64 j-tiles, swz128 (R11/R12, passing).
// ---------------------------------------------------------------------------
__global__ __launch_bounds__(256)
void states_kernel(const u16* __restrict__ xT, const u16* __restrict__ BT,
                   const float* __restrict__ dt, const float* __restrict__ seg,
                   u16* __restrict__ statesb) {
    int bid = blockIdx.x;
    int h = bid & 31, c = (bid >> 5) & 7, b = bid >> 8;
    __shared__ float dd[QCH];
    __shared__ __attribute__((aligned(16))) u16 At[64 * 64];    //  8 KB
    __shared__ __attribute__((aligned(16))) u16 Bt[128 * 64];   // 16 KB
    const int t = threadIdx.x;
    const int lane = t & 63, wave = t >> 6;
    const int wr = wave >> 1, wc = wave & 1;
    const int fr = lane & 15, fq = lane >> 4;
    const int fr7 = fr & 7;
    const int l0 = b * SEQ + c * QCH;
    {
        float seg_last = seg[(size_t)(l0 + QCH - 1) * NH + h];
        dd[t] = dt[(size_t)(l0 + t) * NH + h] *
                __expf(seg_last - seg[(size_t)(l0 + t) * NH + h]);
    }
    __syncthreads();
    f32x4 acc[2][4];
#pragma unroll
    for (int m = 0; m < 2; ++m)
#pragma unroll
        for (int n = 0; n < 4; ++n) acc[m][n] = 0;

    for (int j0 = 0; j0 < QCH; j0 += 64) {
#pragma unroll
        for (int q = 0; q < 2; ++q) {
            int ch = t + 256 * q;
            int row = ch >> 3, slot = ch & 7;
            u16x8 v = *(const u16x8*)&xT[(size_t)(b * SEQ + h * PDIM + row) * SEQ +
                                         c * QCH + j0 + slot * 8];
            u16x8 o;
#pragma unroll
            for (int e = 0; e < 8; ++e)
                o[e] = f2bf(bf2f(v[e]) * dd[j0 + slot * 8 + e]);
            *(u16x8*)&At[swz128(row, slot)] = o;
        }
#pragma unroll
        for (int q = 0; q < 4; ++q) {
            int ch = t + 256 * q;
            int row = ch >> 3, slot = ch & 7;
            gload_lds16(BT + (size_t)(b * STATE + row) * SEQ + c * QCH + j0 +
                            8 * (slot ^ (row & 7)), &Bt[ch * 8]);
        }
        __syncthreads();
#pragma unroll
        for (int ks = 0; ks < 2; ++ks) {
            bf16x8 af[2], bw[4];
#pragma unroll
            for (int m = 0; m < 2; ++m) {
                int r = wr * 32 + m * 16 + fr;
                af[m] = *(const bf16x8*)&At[r * 64 + ((ks * 4 + fq) ^ fr7) * 8];
            }
#pragma unroll
            for (int n = 0; n < 4; ++n) {
                int r = wc * 64 + n * 16 + fr;
                bw[n] = *(const bf16x8*)&Bt[r * 64 + ((ks * 4 + fq) ^ fr7) * 8];
            }
#pragma unroll
            for (int m = 0; m < 2; ++m)
#pragma unroll
                for (int n = 0; n < 4; ++n)
                    acc[m][n] = __builtin_amdgcn_mfma_f32_16x16x32_bf16(
                        af[m], bw[n], acc[m][n], 0, 0, 0);
        }
        __syncthreads();
    }
    size_t base = ((((size_t)b * NCHUNK + c) * NH + h) * PDIM) * STATE;
#pragma unroll
    for (int m = 0; m < 2; ++m)
#pragma unroll
        for (int n = 0; n < 4; ++n) {
            int p = wr * 32 + m * 16 + fq * 4;
            int nn = wc * 64 + n * 16 + fr;
#pragma unroll
            for (int r = 0; r < 4; ++r)
                statesb[base + (size_t)(p + r) * STATE + nn] = f2bf(acc[m][n][r]);
        }
}

// ---------------------------------------------------------------------------
// Inter-chunk scan: reads bf16 states, f32 carry, writes bf16 prev only.
// ---------------------------------------------------------------------------
__global__ void scan_kernel(const u16* __restrict__ statesb,
                            const float* __restrict__ seg,
                            u16* __restrict__ prevbf) {
    int tid = blockIdx.x * blockDim.x + threadIdx.x;
    int n = tid & 127, p = (tid >> 7) & 63, h = (tid >> 13) & 31, b = tid >> 18;
    float carry = 0.f;
    for (int c = 0; c < NCHUNK; ++c) {
        size_t idx = ((((size_t)b * NCHUNK + c) * NH + h) * PDIM + p) * STATE + n;
        float st = bf2f(statesb[idx]);
        prevbf[idx] = f2bf(carry);
        float dec = __expf(seg[(size_t)(b*SEQ + c*QCH + QCH - 1) * NH + h]);
        carry = carry * dec + st;
    }
}

// ---------------------------------------------------------------------------
// Fused Yo + Yd (+ D*x via M-diagonal) -> y (bf16).  (R11/R12, passing)
// ---------------------------------------------------------------------------
__global__ __launch_bounds__(256)
void ydo_kernel(const u16* __restrict__ xT, const u16* __restrict__ Cbf,
                const u16* __restrict__ prevbf, const u16* __restrict__ CBbf,
                const float* __restrict__ dt, const float* __restrict__ seg,
                const float* __restrict__ Dv, u16* __restrict__ yb) {
    int bid = blockIdx.x;
    int h = bid & 31, c = (bid >> 5) & 7, b = bid >> 8;
    __shared__ float seg_s[QCH], sge_s[QCH], dtv_s[QCH];
    __shared__ __attribute__((aligned(16))) u16 big[QCH * 64];   // 32 KB
    __shared__ __attribute__((aligned(16))) u16 small[64 * 64];  // 8 KB
    const int t = threadIdx.x;
    const int lane = t & 63, w = t >> 6;
    const int fr = lane & 15, fq = lane >> 4;
    const int l0 = b * SEQ + c * QCH;
    const float Dh = Dv[h];
    {
        float sv = seg[(size_t)(l0 + t) * NH + h];
        seg_s[t] = sv;
        sge_s[t] = __expf(sv);
        dtv_s[t] = dt[(size_t)(l0 + t) * NH + h];
    }
    __syncthreads();
    f32x4 acc[4][4];
#pragma unroll
    for (int m = 0; m < 4; ++m)
#pragma unroll
        for (int n = 0; n < 4; ++n) acc[m][n] = 0;

    const size_t pvbase = ((((size_t)b * NCHUNK + c) * NH + h) * PDIM) * STATE;
    for (int kc = 0; kc < 2; ++kc) {
#pragma unroll
        for (int q = 0; q < 8; ++q) {
            int ch = t + 256 * q;
            int row = ch >> 3, slot = ch & 7;
            gload_lds16(Cbf + (size_t)(l0 + row) * STATE + kc * 64 +
                            8 * (slot ^ (row & 7)), &big[ch * 8]);
        }
#pragma unroll
        for (int q = 0; q < 2; ++q) {
            int ch = t + 256 * q;
            int row = ch >> 3, slot = ch & 7;
            gload_lds16(prevbf + pvbase + (size_t)row * STATE + kc * 64 +
                            8 * (slot ^ (row & 7)), &small[ch * 8]);
        }
        __syncthreads();
#pragma unroll
        for (int ks2 = 0; ks2 < 2; ++ks2) {
            bf16x8 af[4], bw[4];
#pragma unroll
            for (int m = 0; m < 4; ++m)
                af[m] = *(const bf16x8*)&big[swz128(64 * m + 16 * w + fr,
                                                   ks2 * 4 + fq)];
#pragma unroll
            for (int n = 0; n < 4; ++n)
                bw[n] = *(const bf16x8*)&small[swz128(16 * n + fr,
                                                      ks2 * 4 + fq)];
#pragma unroll
            for (int m = 0; m < 4; ++m)
#pragma unroll
                for (int n = 0; n < 4; ++n)
                    acc[m][n] = __builtin_amdgcn_mfma_f32_16x16x32_bf16(
                        af[m], bw[n], acc[m][n], 0, 0, 0);
        }
        __syncthreads();
    }
#pragma unroll
    for (int m = 0; m < 4; ++m)
#pragma unroll
        for (int n = 0; n < 4; ++n)
#pragma unroll
            for (int r = 0; r < 4; ++r)
                acc[m][n][r] *= sge_s[64 * m + 16 * w + fq * 4 + r];

    const u16* CBrow = CBbf + (size_t)(b * NCHUNK + c) * QCH * QCH;
    for (int jt = 0; jt < 4; ++jt) {
        const int j0 = jt * 64;
        const int c4 = (t & 15) * 4;
        for (int r = j0 + (t >> 4); r < QCH; r += 16) {
            u16x4 cb4 = *(const u16x4*)&CBrow[(size_t)r * QCH + j0 + c4];
            u16x4 o4;
            int d = r - j0;
#pragma unroll
            for (int e = 0; e < 4; ++e) {
                int mcol = c4 + e;
                float v = 0.f;
                if (mcol <= d) {
                    v = bf2f(cb4[e]) * __expf(seg_s[r] - seg_s[j0 + mcol]) *
                        dtv_s[j0 + mcol];
                    if (mcol == d) v += Dh;
                }
                o4[e] = f2bf(v);
            }
            *(u16x4*)&big[((r * 128 + c4 * 2) ^ ((r & 7) << 4)) >> 1] = o4;
        }
#pragma unroll
        for (int q = 0; q < 2; ++q) {
            int chunk = t + 256 * q;
            int row = chunk >> 3, slot = chunk & 7;
            gload_lds16(xT + (size_t)(b * SEQ + h * PDIM + row) * SEQ +
                            c * QCH + j0 + 8 * (slot ^ (row & 7)),
                        &small[chunk * 8]);
        }
        __syncthreads();
#pragma unroll
        for (int ks = 0; ks < 2; ++ks) {
#pragma unroll
            for (int m = 0; m < 4; ++m) {
                if (64 * m + 16 * w >= j0) {
                    bf16x8 af = *(const bf16x8*)
                        &big[swz128(64 * m + 16 * w + fr, ks * 4 + fq)];
#pragma unroll
                    for (int n = 0; n < 4; ++n) {
                        bf16x8 bw = *(const bf16x8*)
                            &small[swz128(16 * n + fr, ks * 4 + fq)];
                        acc[m][n] = __builtin_amdgcn_mfma_f32_16x16x32_bf16(
                            af, bw, acc[m][n], 0, 0, 0);
                    }
                }
            }
        }
        __syncthreads();
    }
#pragma unroll
    for (int m = 0; m < 4; ++m) {
        int i = 64 * m + 16 * w + fq * 4;
#pragma unroll
        for (int n = 0; n < 4; ++n) {
            int p = 16 * n + fr;
#pragma unroll
            for (int r = 0; r < 4; ++r)
                yb[(size_t)(l0 + i + r) * INTER + h * PDIM + p] =
                    f2bf(acc[m][n][r]);
        }
    }
}

// ---------------------------------------------------------------------------
// yg = y * silu(z); RMS-norm; * norm_weight.  In place on bf16 y.
// ---------------------------------------------------------------------------
__global__ __launch_bounds__(256)
void gatenorm_kernel(u16* __restrict__ yb, const u16* __restrict__ zxb,
                     const float* __restrict__ nw) {
    int bl = blockIdx.x;
    int t = threadIdx.x;
    u16x8 yv8 = *(const u16x8*)&yb[(size_t)bl * INTER + t * 8];
    u16x8 zv8 = *(const u16x8*)&zxb[(size_t)bl * DPROJ + t * 8];
    float g[8];
    float ss = 0.f;
#pragma unroll
    for (int i = 0; i < 8; ++i) {
        float yv = bf2f(yv8[i]), zv = bf2f(zv8[i]);
        g[i] = yv * (zv / (1.f + __expf(-zv)));
        ss += g[i] * g[i];
    }
    for (int off = 32; off > 0; off >>= 1) ss += __shfl_xor(ss, off, 64);
    __shared__ float red[4];
    if ((t & 63) == 0) red[t >> 6] = ss;
    __syncthreads();
    float tot = red[0] + red[1] + red[2] + red[3];
    float scale = rsqrtf(tot / INTER + 1e-6f);
    const float* nwp = nw + t * 8;
    u16x8 o;
#pragma unroll
    for (int i = 0; i < 8; ++i) o[i] = f2bf(g[i] * scale * nwp[i]);
    *(u16x8*)&yb[(size_t)bl * INTER + t * 8] = o;
}

// ---------------------------------------------------------------------------
extern "C" void kernel_launch(void* const* d_in, const int* in_sizes, int n_in,
                              void* d_out, int out_size, void* d_ws, size_t ws_size,
                              hipStream_t stream) {
    const float* hidden     = (const float*)d_in[0];
    const float* in_proj_w  = (const float*)d_in[1];
    const float* conv_w     = (const float*)d_in[2];
    const float* conv_b     = (const float*)d_in[3];
    const float* dt_bias    = (const float*)d_in[4];
    const float* A_log      = (const float*)d_in[5];
    const float* Dv         = (const float*)d_in[6];
    const float* norm_w     = (const float*)d_in[7];
    const float* out_proj_w = (const float*)d_in[8];
    float* out = (float*)d_out;

    // layout (u16 units unless noted) — identical to round 12 (passing, best)
    u16* wsu    = (u16*)d_ws;
    u16* zxb    = wsu;                                        // 17,956,864
    u16* statesb= zxb    + (size_t)BL * DPROJ;                // 16,777,216
    u16* prevbf = statesb+ (size_t)BATCH*NCHUNK*NH*PDIM*STATE;// 16,777,216
    u16* yb     = prevbf + (size_t)BATCH*NCHUNK*NH*PDIM*STATE;//  8,388,608
    u16* xT     = yb     + (size_t)BL * INTER;                //  8,388,608
    u16* BT     = xT     + (size_t)BL * INTER;                //    524,288
    u16* Bbf    = BT     + (size_t)BATCH * STATE * SEQ;       //    524,288
    u16* Cbf    = Bbf    + (size_t)BL * STATE;                //    524,288
    u16* W2bf   = Cbf    + (size_t)BL * STATE;                //  2,097,152
    float* dtraw = (float*)(W2bf + (size_t)HID * INTER);      //    131,072 f32
    float* dtb   = dtraw + (size_t)BL * NH;                   //    131,072 f32
    float* segb  = dtb   + (size_t)BL * NH;                   //    131,072 f32
    u16*  CBbf   = (u16*)(segb + (size_t)BL * NH);            //  1,048,576 u16
    // aliases into dead regions:
    u16* Abf = statesb;                       // dead once in_proj GEMM done
    u16* Wbf = statesb + (size_t)BL * HID;
    // f32 kpart: 2 partials x BL*HID f32 = 33.5 MB inside zxb (35.9 MB,
    // dead after gatenorm) — exact R12 placement.
    float* kpart = (float*)zxb;

    // 1. fused f32->bf16 conversions
    {
        long total = (long)BL*HID + (long)DPROJ_PAD*HID + (long)HID*INTER;
        cvt_all<<<(int)(total / 2048), 256, 0, stream>>>(
            hidden, in_proj_w, out_proj_w, Abf, Wbf, W2bf);
    }

    // 2. in_proj: zxb(bf16) = Abf @ Wbf^T, dt cols also f32 -> dtraw
    gemm_in_kernel<<<dim3(DPROJ_PAD/128, BL/256), 512, 0, stream>>>(
        Abf, Wbf, zxb, dtraw, DPROJ, DPROJ, HID);

    dtseg_kernel<<<BATCH * NCHUNK * NH, 256, 0, stream>>>(
        dtraw, dt_bias, A_log, dtb, segb);
    convT_kernel<<<dim3(CONV_DIM/64, SEQ/64, BATCH), 256, 0, stream>>>(
        zxb, conv_w, conv_b, xT, BT, Bbf, Cbf);
    cb_kernel<<<dim3(4, 4, BATCH*NCHUNK), 256, 0, stream>>>(Cbf, Bbf, CBbf);
    states_kernel<<<BATCH * NCHUNK * NH, 256, 0, stream>>>(
        xT, BT, dtb, segb, statesb);
    scan_kernel<<<(BATCH * NH * PDIM * STATE) / 256, 256, 0, stream>>>(
        statesb, segb, prevbf);
    ydo_kernel<<<BATCH * NCHUNK * NH, 256, 0, stream>>>(
        xT, Cbf, prevbf, CBbf, dtb, segb, Dv, yb);
    gatenorm_kernel<<<BL, 256, 0, stream>>>(yb, zxb, norm_w);

    // out_proj: 128^2 tile, split-K=2, f32 partials; then reduce (R12)
    gemm_ks_kernel<<<dim3(HID/128, BL/128, 2), 256, 0, stream>>>(
        yb, W2bf, kpart, BL, HID, INTER, INTER/2);
    addred_kernel<<<((long)BL*HID)/1024, 256, 0, stream>>>(
        kpart, out, (long)BL*HID);
}